// Round 1
// baseline (6757.806 us; speedup 1.0000x reference)
//
#include <hip/hip_runtime.h>
#include <math.h>

// ---------------- problem constants ----------------
#define V_VOX 12000
#define T_PTS 35
#define DD 10
#define HH 200
#define WW 176
#define EPSV 1e-5f

// padded dims (1-cell halo on every side of D,H,W)
#define DP 12
#define HP 202
#define WP 178
#define PLN (HP * WP)        // 35956
#define VOLCH (DP * PLN)     // 431472 elems per channel (padded)
#define NPIX (DD * HH * WW)  // 352000
#define HWPIX (HH * WW)      // 35200

// ---------------- workspace layout (float offsets) ----------------
// wtA [32*27*64], wtB [64*27*64], wtR1 [64*9*128]
#define WTA_OFF 0
#define WTB_OFF 55296
#define WTR1_OFF 165888
#define STATS_OFF 239616   // 1024 floats: sums[0:320), coeffs[320:640)
#define FEATS_OFF 240640   // 12000*32
#define VOLP_OFF 624640    // 32*VOLCH = 13,807,104  (reused later: planep, r1out)
#define Y_OFF 14431744     // 64*NPIX = 22,528,000   (y1 then y2)
#define X1P_OFF 36959744   // 64*VOLCH = 27,614,208
// total = 64,573,952 floats = 258.3 MB

// stats sub-offsets (relative to STATS_OFF)
#define S_BN0S 0
#define S_BN0Q 32
#define S_BN1S 64
#define S_BN1Q 128
#define S_BN2S 192
#define S_BN2Q 256
#define C0A 320
#define C0B 352
#define C1A 384
#define C1B 448
#define C2A 512
#define C2B 576

// planep / r1out live inside the (dead) volume region
#define PLANEP_OFF VOLP_OFF
#define R1OUT_OFF (VOLP_OFF + 2301184)

// ---------------- weight transpose: w[oc][ic][tap] -> wt[(ic*TAPS+tap)*OC+oc] ----------------
__global__ void k_transpose_w(const float* __restrict__ w, float* __restrict__ wt,
                              int IC, int TAPS, int OC) {
    int i = blockIdx.x * 256 + threadIdx.x;
    int total = IC * TAPS * OC;
    if (i >= total) return;
    int oc = i % OC;
    int r = i / OC;
    int tap = r % TAPS;
    int ic = r / TAPS;
    wt[i] = w[(oc * IC + ic) * TAPS + tap];
}

// ---------------- VFE: BN0 batch stats over h = vox @ w_lin^T + b_lin ----------------
__global__ void k_vfe_stats(const float4* __restrict__ vox, const float* __restrict__ w_lin,
                            const float* __restrict__ b_lin, float* __restrict__ stats) {
    int tid = blockIdx.x * blockDim.x + threadIdx.x;
    const int np = V_VOX * T_PTS;  // 420000
    float s[32], q[32];
#pragma unroll
    for (int c = 0; c < 32; c++) { s[c] = 0.f; q[c] = 0.f; }
    for (int p = tid; p < np; p += gridDim.x * blockDim.x) {
        float4 v = vox[p];
#pragma unroll
        for (int c = 0; c < 32; c++) {
            float4 w = ((const float4*)w_lin)[c];
            float d = v.x * w.x + v.y * w.y + v.z * w.z + v.w * w.w + b_lin[c];
            s[c] += d;
            q[c] += d * d;
        }
    }
#pragma unroll
    for (int c = 0; c < 32; c++) {
        float a = s[c], b = q[c];
        for (int m = 32; m > 0; m >>= 1) { a += __shfl_xor(a, m); b += __shfl_xor(b, m); }
        if ((threadIdx.x & 63) == 0) {
            atomicAdd(&stats[S_BN0S + c], a);
            atomicAdd(&stats[S_BN0Q + c], b);
        }
    }
}

// ---------------- BN finalize: a = g*rsqrt(var+eps), b = be - mean*a ----------------
__global__ void k_bn_final(const float* __restrict__ ss, const float* __restrict__ sq,
                           const float* __restrict__ g, const float* __restrict__ be,
                           float* __restrict__ ca, float* __restrict__ cb, int C, float invN) {
    int c = threadIdx.x;
    if (c >= C) return;
    float m = ss[c] * invN;
    float v = sq[c] * invN - m * m;
    float a = g[c] * rsqrtf(v + EPSV);
    ca[c] = a;
    cb[c] = be[c] - m * a;
}

// ---------------- VFE: relu(bn(h)) max over T -> feats [V][32] ----------------
__global__ void k_vfe_max(const float4* __restrict__ vox, const float* __restrict__ w_lin,
                          const float* __restrict__ b_lin, const float* __restrict__ ca,
                          const float* __restrict__ cb, float* __restrict__ feats) {
    int id = blockIdx.x * 256 + threadIdx.x;
    if (id >= V_VOX * 32) return;
    int c = id & 31;
    int v = id >> 5;
    float4 w = ((const float4*)w_lin)[c];
    float bl = b_lin[c], A = ca[c], B = cb[c];
    float m = 0.f;  // relu floor
    for (int t = 0; t < T_PTS; t++) {
        float4 p = vox[v * T_PTS + t];
        float d = p.x * w.x + p.y * w.y + p.z * w.z + p.w * w.w + bl;
        m = fmaxf(m, A * d + B);
    }
    feats[id] = m;
}

// ---------------- scatter feats into padded dense volume ----------------
__global__ void k_scatter(const float* __restrict__ feats, const int* __restrict__ coords,
                          float* __restrict__ volp) {
    int id = blockIdx.x * 256 + threadIdx.x;
    if (id >= V_VOX * 32) return;
    int c = id & 31;
    int v = id >> 5;
    int z = coords[v * 3 + 0];
    int y = coords[v * 3 + 1];
    int x = coords[v * 3 + 2];
    volp[c * VOLCH + (z + 1) * PLN + (y + 1) * WP + (x + 1)] = feats[v * 32 + c];
}

// ---------------- direct 3D conv (padded input, 64 oc per thread) + BN stats ----------------
template <int IC>
__global__ __launch_bounds__(256, 2) void k_conv3d(const float* __restrict__ inp,
                                                   const float* __restrict__ wt,
                                                   const float* __restrict__ bias,
                                                   float* __restrict__ out,
                                                   float* __restrict__ ssum,
                                                   float* __restrict__ ssq) {
    unsigned p = blockIdx.x * 256 + threadIdx.x;  // NPIX=352000 divisible by 256
    unsigned z = p / HWPIX;
    unsigned r = p - z * HWPIX;
    unsigned yy = r / WW;
    unsigned xx = r - yy * WW;
    float acc[64];
#pragma unroll
    for (int o = 0; o < 64; o++) acc[o] = bias[o];
    const float* ibase = inp + z * PLN + yy * WP + xx;
#pragma unroll 1
    for (int ic = 0; ic < IC; ic++) {
        const float* icb = ibase + ic * VOLCH;
#pragma unroll 1
        for (int dz = 0; dz < 3; dz++) {
#pragma unroll 1
            for (int dy = 0; dy < 3; dy++) {
                const float* rb = icb + dz * PLN + dy * WP;
#pragma unroll
                for (int dx = 0; dx < 3; dx++) {
                    float v = rb[dx];
                    const float4* w4 = (const float4*)(wt + (ic * 27 + dz * 9 + dy * 3 + dx) * 64);
#pragma unroll
                    for (int k = 0; k < 16; k++) {
                        float4 wv = w4[k];
                        acc[4 * k + 0] += v * wv.x;
                        acc[4 * k + 1] += v * wv.y;
                        acc[4 * k + 2] += v * wv.z;
                        acc[4 * k + 3] += v * wv.w;
                    }
                }
            }
        }
    }
#pragma unroll
    for (int o = 0; o < 64; o++) out[o * NPIX + p] = acc[o];
    // per-channel batch stats (sum, sumsq) via wave reduce + atomics
#pragma unroll
    for (int o = 0; o < 64; o++) {
        float a = acc[o], q = acc[o] * acc[o];
        for (int m = 32; m > 0; m >>= 1) { a += __shfl_xor(a, m); q += __shfl_xor(q, m); }
        if ((threadIdx.x & 63) == 0) {
            atomicAdd(&ssum[o], a);
            atomicAdd(&ssq[o], q);
        }
    }
}

// ---------------- activate: x1p = relu(a*y1+b) into padded buffer (halo=0) ----------------
__global__ void k_activate(const float* __restrict__ y1, const float* __restrict__ ca,
                           const float* __restrict__ cb, float* __restrict__ xp) {
    unsigned id = blockIdx.x * 256 + threadIdx.x;  // 64*VOLCH divisible by 256
    unsigned c = id / VOLCH;
    unsigned r = id - c * VOLCH;
    unsigned zp = r / PLN;
    r -= zp * PLN;
    unsigned yp = r / WP;
    unsigned xq = r - yp * WP;
    float val = 0.f;
    if (zp >= 1 && zp <= DD && yp >= 1 && yp <= HH && xq >= 1 && xq <= WW) {
        float v = y1[c * NPIX + (zp - 1) * HWPIX + (yp - 1) * WW + (xq - 1)];
        val = fmaxf(ca[c] * v + cb[c], 0.f);
    }
    xp[id] = val;
}

// ---------------- BN2 + relu + mean over depth -> padded plane ----------------
__global__ void k_depthmean(const float* __restrict__ y2, const float* __restrict__ ca,
                            const float* __restrict__ cb, float* __restrict__ planep) {
    unsigned id = blockIdx.x * 256 + threadIdx.x;  // 64*PLN divisible by 256
    unsigned c = id / PLN;
    unsigned r = id - c * PLN;
    unsigned yp = r / WP;
    unsigned xq = r - yp * WP;
    float val = 0.f;
    if (yp >= 1 && yp <= HH && xq >= 1 && xq <= WW) {
        float A = ca[c], B = cb[c], s = 0.f;
        const float* base = y2 + c * NPIX + (yp - 1) * WW + (xq - 1);
#pragma unroll
        for (int z = 0; z < DD; z++) s += fmaxf(A * base[z * HWPIX] + B, 0.f);
        val = s * 0.1f;
    }
    planep[id] = val;
}

// ---------------- 2D conv 3x3, 64ic -> 64oc slice (grid.y selects oc half) + relu ----------------
__global__ __launch_bounds__(64) void k_conv2d_r1(const float* __restrict__ planep,
                                                  const float* __restrict__ wt,
                                                  const float* __restrict__ bias,
                                                  float* __restrict__ out) {
    unsigned p = blockIdx.x * 64 + threadIdx.x;  // 35200 divisible by 64
    unsigned ocbase = blockIdx.y * 64;
    unsigned yy = p / WW;
    unsigned xx = p - yy * WW;
    float acc[64];
#pragma unroll
    for (int o = 0; o < 64; o++) acc[o] = bias[ocbase + o];
    const float* ib = planep + yy * WP + xx;
#pragma unroll 1
    for (int ic = 0; ic < 64; ic++) {
        const float* icb = ib + ic * PLN;
#pragma unroll 1
        for (int dy = 0; dy < 3; dy++) {
            const float* rb = icb + dy * WP;
#pragma unroll
            for (int dx = 0; dx < 3; dx++) {
                float v = rb[dx];
                const float4* w4 = (const float4*)(wt + (ic * 9 + dy * 3 + dx) * 128 + ocbase);
#pragma unroll
                for (int k = 0; k < 16; k++) {
                    float4 wv = w4[k];
                    acc[4 * k + 0] += v * wv.x;
                    acc[4 * k + 1] += v * wv.y;
                    acc[4 * k + 2] += v * wv.z;
                    acc[4 * k + 3] += v * wv.w;
                }
            }
        }
    }
#pragma unroll
    for (int o = 0; o < 64; o++) out[(ocbase + o) * HWPIX + p] = fmaxf(acc[o], 0.f);
}

// ---------------- 1x1 conv 128->8 + box transforms -> d_out ----------------
__global__ void k_conv2d_r2(const float* __restrict__ r1o, const float* __restrict__ w,
                            const float* __restrict__ bias, float* __restrict__ outp) {
    unsigned p = blockIdx.x * 256 + threadIdx.x;
    if (p >= HWPIX) return;
    float acc[8];
#pragma unroll
    for (int o = 0; o < 8; o++) acc[o] = bias[o];
#pragma unroll 4
    for (int ic = 0; ic < 128; ic++) {
        float v = r1o[ic * HWPIX + p];
#pragma unroll
        for (int o = 0; o < 8; o++) acc[o] += v * w[o * 128 + ic];
    }
    outp[0 * HWPIX + p] = acc[0];
    outp[1 * HWPIX + p] = acc[1];
    outp[2 * HWPIX + p] = acc[2];
    outp[3 * HWPIX + p] = expf(acc[3]);
    outp[4 * HWPIX + p] = expf(acc[4]);
    outp[5 * HWPIX + p] = expf(acc[5]);
    outp[6 * HWPIX + p] = tanhf(acc[6]);
    outp[7 * HWPIX + p] = 1.f / (1.f + expf(-acc[7]));
}

// ---------------- host launch ----------------
extern "C" void kernel_launch(void* const* d_in, const int* in_sizes, int n_in,
                              void* d_out, int out_size, void* d_ws, size_t ws_size,
                              hipStream_t stream) {
    const float4* voxels = (const float4*)d_in[0];
    const int* coords = (const int*)d_in[1];
    const float* w_lin = (const float*)d_in[2];
    const float* b_lin = (const float*)d_in[3];
    const float* g_bn0 = (const float*)d_in[4];
    const float* be_bn0 = (const float*)d_in[5];
    const float* w_c3a = (const float*)d_in[6];
    const float* b_c3a = (const float*)d_in[7];
    const float* g_bn1 = (const float*)d_in[8];
    const float* be_bn1 = (const float*)d_in[9];
    const float* w_c3b = (const float*)d_in[10];
    const float* b_c3b = (const float*)d_in[11];
    const float* g_bn2 = (const float*)d_in[12];
    const float* be_bn2 = (const float*)d_in[13];
    const float* w_r1 = (const float*)d_in[14];
    const float* b_r1 = (const float*)d_in[15];
    const float* w_r2 = (const float*)d_in[16];
    const float* b_r2 = (const float*)d_in[17];

    float* ws = (float*)d_ws;
    float* wtA = ws + WTA_OFF;
    float* wtB = ws + WTB_OFF;
    float* wtR1 = ws + WTR1_OFF;
    float* S = ws + STATS_OFF;
    float* feats = ws + FEATS_OFF;
    float* volp = ws + VOLP_OFF;
    float* Y = ws + Y_OFF;     // y1, then y2
    float* x1p = ws + X1P_OFF;
    float* planep = ws + PLANEP_OFF;
    float* r1out = ws + R1OUT_OFF;
    float* outp = (float*)d_out;

    // zero accumulators + padded volume (per-call init; harness does not re-poison)
    hipMemsetAsync(S, 0, 320 * sizeof(float), stream);
    hipMemsetAsync(volp, 0, (size_t)32 * VOLCH * sizeof(float), stream);

    // weight transposes -> [ic][tap][oc]
    k_transpose_w<<<216, 256, 0, stream>>>(w_c3a, wtA, 32, 27, 64);
    k_transpose_w<<<432, 256, 0, stream>>>(w_c3b, wtB, 64, 27, 64);
    k_transpose_w<<<288, 256, 0, stream>>>(w_r1, wtR1, 64, 9, 128);

    // VFE
    k_vfe_stats<<<256, 256, 0, stream>>>(voxels, w_lin, b_lin, S);
    k_bn_final<<<1, 64, 0, stream>>>(S + S_BN0S, S + S_BN0Q, g_bn0, be_bn0,
                                     S + C0A, S + C0B, 32, 1.f / 420000.f);
    k_vfe_max<<<1500, 256, 0, stream>>>(voxels, w_lin, b_lin, S + C0A, S + C0B, feats);
    k_scatter<<<1500, 256, 0, stream>>>(feats, coords, volp);

    // conv3a + BN1
    k_conv3d<32><<<1375, 256, 0, stream>>>(volp, wtA, b_c3a, Y, S + S_BN1S, S + S_BN1Q);
    k_bn_final<<<1, 64, 0, stream>>>(S + S_BN1S, S + S_BN1Q, g_bn1, be_bn1,
                                     S + C1A, S + C1B, 64, 1.f / 352000.f);
    k_activate<<<107868, 256, 0, stream>>>(Y, S + C1A, S + C1B, x1p);

    // conv3b + BN2 (y2 overwrites y1 region; conv3b reads x1p only)
    k_conv3d<64><<<1375, 256, 0, stream>>>(x1p, wtB, b_c3b, Y, S + S_BN2S, S + S_BN2Q);
    k_bn_final<<<1, 64, 0, stream>>>(S + S_BN2S, S + S_BN2Q, g_bn2, be_bn2,
                                     S + C2A, S + C2B, 64, 1.f / 352000.f);

    // BN2 + relu + depth mean -> padded plane (overwrites dead volume region)
    k_depthmean<<<8989, 256, 0, stream>>>(Y, S + C2A, S + C2B, planep);

    // RPN head
    k_conv2d_r1<<<dim3(550, 2), 64, 0, stream>>>(planep, wtR1, b_r1, r1out);
    k_conv2d_r2<<<138, 256, 0, stream>>>(r1out, w_r2, b_r2, outp);
}

// Round 2
// 625.815 us; speedup vs baseline: 10.7984x; 10.7984x over previous
//
#include <hip/hip_runtime.h>
#include <math.h>

// ---------------- problem constants ----------------
#define V_VOX 12000
#define T_PTS 35
#define DD 10
#define HH 200
#define WW 176
#define EPSV 1e-5f

#define DP 12
#define HP 202
#define WP 178
#define PPLN (HP * WP)          // 35956 padded plane pixels
#define PVOX (DP * PPLN)        // 431472 padded volume pixels
#define NPIX (DD * HH * WW)     // 352000
#define HWPIX (HH * WW)         // 35200

typedef _Float16 half_t;
typedef _Float16 f16x8 __attribute__((ext_vector_type(8)));
typedef float f32x4 __attribute__((ext_vector_type(4)));

// ---------------- workspace layout (BYTE offsets, all 256-aligned) ----------------
#define WPA_OFF 0           // 27*1*4*512 halves = 110592 B
#define WPB_OFF 110592      // 27*2*4*512 halves = 221184 B
#define WPR1_OFF 331776     // 9*2*8*512 halves = 147456 B
#define STATS_OFF 479232    // 1024 floats
#define FEATS_OFF 483328    // 12000*32 f32 = 1536000 B
#define VOLP_OFF 2019328    // PVOX*32 halves = 27614208 B
#define X1P_OFF 29633536    // PVOX*64 halves = 55228416 B
#define Y_OFF 84861952      // NPIX*64 halves = 45056000 B  (y1 then y2)
#define PLANE_OFF 129917952 // PPLN*64 halves = 4602368 B
#define R1OUT_OFF 134520320 // HWPIX*128 halves = 9011200 B
// total 143531520 B = 143.5 MB

// stats float sub-offsets
#define S_BN0S 0
#define S_BN0Q 32
#define S_BN1S 64
#define S_BN1Q 128
#define S_BN2S 192
#define S_BN2Q 256
#define C0A 320
#define C0B 352
#define C1A 384
#define C1B 448
#define C2A 512
#define C2B 576

// ---------------- weight pack: w[oc][ic][tap] -> per-lane MFMA B fragments ----------------
// wp index = (((tap*KH + kh)*OCT + ot)*64 + lane)*8 + j
// oc = ot*16 + (lane&15); ic = kh*32 + (lane>>4)*8 + j
__global__ void k_pack(const float* __restrict__ w, half_t* __restrict__ wp,
                       int IC, int NT, int OC) {
    int id = blockIdx.x * 256 + threadIdx.x;
    int OCT = OC >> 4, KH = IC >> 5;
    int total = NT * KH * OCT * 512;
    if (id >= total) return;
    int j = id & 7;
    int lane = (id >> 3) & 63;
    int rest = id >> 9;
    int ot = rest % OCT; rest /= OCT;
    int kh = rest % KH;
    int tap = rest / KH;
    int oc = ot * 16 + (lane & 15);
    int ic = kh * 32 + (lane >> 4) * 8 + j;
    wp[id] = (half_t)w[(oc * IC + ic) * NT + tap];
}

// ---------------- VFE: BN0 batch stats (2 scalar accumulators/thread, no spill) ----------------
__global__ void k_vfe_stats(const float4* __restrict__ vox, const float* __restrict__ w_lin,
                            const float* __restrict__ b_lin, float* __restrict__ S) {
    int tid = blockIdx.x * 256 + threadIdx.x;
    int c = threadIdx.x & 31;
    float4 w = ((const float4*)w_lin)[c];
    float bl = b_lin[c];
    float s = 0.f, q = 0.f;
    const int np = V_VOX * T_PTS;
    int stride = gridDim.x * 8;  // (gridDim*256)>>5
    for (int p = tid >> 5; p < np; p += stride) {
        float4 v = vox[p];
        float d = v.x * w.x + v.y * w.y + v.z * w.z + v.w * w.w + bl;
        s += d;
        q += d * d;
    }
    s += __shfl_xor(s, 32);
    q += __shfl_xor(q, 32);
    if ((threadIdx.x & 63) < 32) {
        atomicAdd(&S[S_BN0S + c], s);
        atomicAdd(&S[S_BN0Q + c], q);
    }
}

// ---------------- BN finalize ----------------
__global__ void k_bn_final(const float* __restrict__ ss, const float* __restrict__ sq,
                           const float* __restrict__ g, const float* __restrict__ be,
                           float* __restrict__ ca, float* __restrict__ cb, int C, float invN) {
    int c = threadIdx.x;
    if (c >= C) return;
    float m = ss[c] * invN;
    float v = sq[c] * invN - m * m;
    float a = g[c] * rsqrtf(v + EPSV);
    ca[c] = a;
    cb[c] = be[c] - m * a;
}

// ---------------- VFE: relu(bn(h)) max over T ----------------
__global__ void k_vfe_max(const float4* __restrict__ vox, const float* __restrict__ w_lin,
                          const float* __restrict__ b_lin, const float* __restrict__ ca,
                          const float* __restrict__ cb, float* __restrict__ feats) {
    int id = blockIdx.x * 256 + threadIdx.x;
    if (id >= V_VOX * 32) return;
    int c = id & 31;
    int v = id >> 5;
    float4 w = ((const float4*)w_lin)[c];
    float bl = b_lin[c], A = ca[c], B = cb[c];
    float m = 0.f;
    for (int t = 0; t < T_PTS; t++) {
        float4 p = vox[v * T_PTS + t];
        float d = p.x * w.x + p.y * w.y + p.z * w.z + p.w * w.w + bl;
        m = fmaxf(m, A * d + B);
    }
    feats[id] = m;
}

// ---------------- scatter feats into padded channel-last f16 volume ----------------
__global__ void k_scatter(const float* __restrict__ feats, const int* __restrict__ coords,
                          half_t* __restrict__ volp) {
    int id = blockIdx.x * 256 + threadIdx.x;
    if (id >= V_VOX * 32) return;
    int c = id & 31;
    int v = id >> 5;
    int z = coords[v * 3 + 0];
    int y = coords[v * 3 + 1];
    int x = coords[v * 3 + 2];
    volp[(((z + 1) * HP + (y + 1)) * WP + (x + 1)) * 32 + c] = (half_t)feats[id];
}

// ---------------- implicit-GEMM conv via MFMA f16 ----------------
// input: padded channel-last [zp][yp][xp][CIN] f16; weights pre-packed fragments;
// output: unpadded pixel-major [p][OCTT*16] f16. Wave tile: 16x * 4y pixels x 64 oc.
template <int KH, int NT, int OCTT, bool TWOD, bool RELU>
__global__ __launch_bounds__(64) void k_conv_mfma(const half_t* __restrict__ in,
                                                  const half_t* __restrict__ wp,
                                                  const float* __restrict__ bias,
                                                  half_t* __restrict__ out) {
    constexpr int CIN = KH * 32;
    const int lane = threadIdx.x;
    const int x0 = blockIdx.x * 16;
    const int y0 = blockIdx.y * 4;
    const int z0 = TWOD ? 0 : blockIdx.z;
    const int ocb = TWOD ? blockIdx.z * 4 : 0;  // octile base (units of 16 oc)

    const int colc = lane & 15, grp = lane >> 4;
    const int aoff = colc * CIN + grp * 8;  // per-lane A-fragment offset (halves)

    f32x4 acc[4][4];
#pragma unroll
    for (int m = 0; m < 4; m++)
#pragma unroll
        for (int n = 0; n < 4; n++) acc[m][n] = (f32x4)(0.f);

#pragma unroll 1
    for (int t = 0; t < NT; t++) {
        int dz, r;
        if (NT == 27) { dz = t / 9; r = t - dz * 9; } else { dz = 0; r = t; }
        int dy = r / 3, dx = r - dy * 3;
        const half_t* ib = in + ((size_t)((z0 + dz) * HP + (y0 + dy)) * WP + (x0 + dx)) * CIN + aoff;
#pragma unroll
        for (int kh = 0; kh < KH; kh++) {
            f16x8 am[4];
#pragma unroll
            for (int m = 0; m < 4; m++)
                am[m] = *(const f16x8*)(ib + m * (WP * CIN) + kh * 32);
            const half_t* wb = wp + ((size_t)(t * KH + kh) * OCTT + ocb) * 512 + lane * 8;
            f16x8 bfr[4];
#pragma unroll
            for (int n = 0; n < 4; n++)
                bfr[n] = *(const f16x8*)(wb + n * 512);
#pragma unroll
            for (int m = 0; m < 4; m++)
#pragma unroll
                for (int n = 0; n < 4; n++)
                    acc[m][n] = __builtin_amdgcn_mfma_f32_16x16x32_f16(am[m], bfr[n], acc[m][n], 0, 0, 0);
        }
    }

    // epilogue: C/D layout col=lane&15 (oc), row=(lane>>4)*4+i (x)
    constexpr int OC = OCTT * 16;
#pragma unroll
    for (int n = 0; n < 4; n++) {
        int oc = (ocb + n) * 16 + colc;
        float bv = bias[oc];
#pragma unroll
        for (int m = 0; m < 4; m++) {
            int yy = y0 + m;
#pragma unroll
            for (int i = 0; i < 4; i++) {
                int xx = x0 + grp * 4 + i;
                float v = acc[m][n][i] + bv;
                if (RELU) v = fmaxf(v, 0.f);
                out[((size_t)(z0 * HH + yy) * WW + xx) * OC + oc] = (half_t)v;
            }
        }
    }
}

// ---------------- per-channel batch stats over f16 y [p][64] ----------------
__global__ void k_stats(const half_t* __restrict__ y, float* __restrict__ ss,
                        float* __restrict__ sq) {
    __shared__ float ls[256], lq[256];
    int tid = threadIdx.x;
    int c = tid & 63;
    float s = 0.f, q = 0.f;
    int p0 = (blockIdx.x * 256 + tid) >> 6;
    int stride = gridDim.x * 4;
    for (int p = p0; p < NPIX; p += stride) {
        float v = (float)y[(size_t)p * 64 + c];
        s += v;
        q += v * v;
    }
    ls[tid] = s;
    lq[tid] = q;
    __syncthreads();
    if (tid < 64) {
        s = ls[tid] + ls[tid + 64] + ls[tid + 128] + ls[tid + 192];
        q = lq[tid] + lq[tid + 64] + lq[tid + 128] + lq[tid + 192];
        atomicAdd(&ss[tid], s);
        atomicAdd(&sq[tid], q);
    }
}

// ---------------- activate: x1p = relu(a*y1+b) into padded channel-last f16 (halo 0) ----------------
__global__ void k_activate(const half_t* __restrict__ y1, const float* __restrict__ ca,
                           const float* __restrict__ cb, half_t* __restrict__ xp) {
    int id = blockIdx.x * 256 + threadIdx.x;
    if (id >= PVOX * 8) return;
    int c0 = (id & 7) * 8;
    int pix = id >> 3;
    int zp = pix / PPLN;
    int rem = pix - zp * PPLN;
    int yp = rem / WP;
    int xq = rem - yp * WP;
    f16x8 o;
    if (zp >= 1 && zp <= DD && yp >= 1 && yp <= HH && xq >= 1 && xq <= WW) {
        size_t p = ((size_t)((zp - 1) * HH + (yp - 1)) * WW + (xq - 1));
        f16x8 v = *(const f16x8*)(y1 + p * 64 + c0);
#pragma unroll
        for (int j = 0; j < 8; j++)
            o[j] = (half_t)fmaxf(ca[c0 + j] * (float)v[j] + cb[c0 + j], 0.f);
    } else {
#pragma unroll
        for (int j = 0; j < 8; j++) o[j] = (half_t)0.f;
    }
    *(f16x8*)(xp + (size_t)pix * 64 + c0) = o;
}

// ---------------- BN2 + relu + depth mean -> padded channel-last plane f16 ----------------
__global__ void k_depthmean(const half_t* __restrict__ y2, const float* __restrict__ ca,
                            const float* __restrict__ cb, half_t* __restrict__ plane) {
    int id = blockIdx.x * 256 + threadIdx.x;  // PPLN*64 = 2301184, divisible by 256
    int c = id & 63;
    int pix = id >> 6;
    int yp = pix / WP;
    int xq = pix - yp * WP;
    float val = 0.f;
    if (yp >= 1 && yp <= HH && xq >= 1 && xq <= WW) {
        float A = ca[c], B = cb[c], s = 0.f;
        const half_t* base = y2 + ((size_t)(yp - 1) * WW + (xq - 1)) * 64 + c;
#pragma unroll
        for (int z = 0; z < DD; z++)
            s += fmaxf(A * (float)base[(size_t)z * HWPIX * 64] + B, 0.f);
        val = s * 0.1f;
    }
    plane[(size_t)pix * 64 + c] = (half_t)val;
}

// ---------------- 1x1 conv 128->8 + box transforms ----------------
__global__ void k_r2(const half_t* __restrict__ r1o, const float* __restrict__ w,
                     const float* __restrict__ bias, float* __restrict__ outp) {
    __shared__ float wsm[1024];
    for (int i = threadIdx.x; i < 1024; i += 256) wsm[i] = w[i];
    __syncthreads();
    int p = blockIdx.x * 256 + threadIdx.x;
    if (p >= HWPIX) return;
    float acc[8];
#pragma unroll
    for (int o = 0; o < 8; o++) acc[o] = bias[o];
    const half_t* rb = r1o + (size_t)p * 128;
#pragma unroll 4
    for (int icb = 0; icb < 128; icb += 8) {
        f16x8 v = *(const f16x8*)(rb + icb);
#pragma unroll
        for (int j = 0; j < 8; j++) {
            float vv = (float)v[j];
#pragma unroll
            for (int o = 0; o < 8; o++) acc[o] += vv * wsm[o * 128 + icb + j];
        }
    }
    outp[0 * HWPIX + p] = acc[0];
    outp[1 * HWPIX + p] = acc[1];
    outp[2 * HWPIX + p] = acc[2];
    outp[3 * HWPIX + p] = expf(acc[3]);
    outp[4 * HWPIX + p] = expf(acc[4]);
    outp[5 * HWPIX + p] = expf(acc[5]);
    outp[6 * HWPIX + p] = tanhf(acc[6]);
    outp[7 * HWPIX + p] = 1.f / (1.f + expf(-acc[7]));
}

// ---------------- host launch ----------------
extern "C" void kernel_launch(void* const* d_in, const int* in_sizes, int n_in,
                              void* d_out, int out_size, void* d_ws, size_t ws_size,
                              hipStream_t stream) {
    const float4* voxels = (const float4*)d_in[0];
    const int* coords = (const int*)d_in[1];
    const float* w_lin = (const float*)d_in[2];
    const float* b_lin = (const float*)d_in[3];
    const float* g_bn0 = (const float*)d_in[4];
    const float* be_bn0 = (const float*)d_in[5];
    const float* w_c3a = (const float*)d_in[6];
    const float* b_c3a = (const float*)d_in[7];
    const float* g_bn1 = (const float*)d_in[8];
    const float* be_bn1 = (const float*)d_in[9];
    const float* w_c3b = (const float*)d_in[10];
    const float* b_c3b = (const float*)d_in[11];
    const float* g_bn2 = (const float*)d_in[12];
    const float* be_bn2 = (const float*)d_in[13];
    const float* w_r1 = (const float*)d_in[14];
    const float* b_r1 = (const float*)d_in[15];
    const float* w_r2 = (const float*)d_in[16];
    const float* b_r2 = (const float*)d_in[17];

    char* ws = (char*)d_ws;
    half_t* wpA = (half_t*)(ws + WPA_OFF);
    half_t* wpB = (half_t*)(ws + WPB_OFF);
    half_t* wpR1 = (half_t*)(ws + WPR1_OFF);
    float* S = (float*)(ws + STATS_OFF);
    float* feats = (float*)(ws + FEATS_OFF);
    half_t* volp = (half_t*)(ws + VOLP_OFF);
    half_t* x1p = (half_t*)(ws + X1P_OFF);
    half_t* Y = (half_t*)(ws + Y_OFF);
    half_t* plane = (half_t*)(ws + PLANE_OFF);
    half_t* r1out = (half_t*)(ws + R1OUT_OFF);
    float* outp = (float*)d_out;

    hipMemsetAsync(S, 0, 320 * sizeof(float), stream);
    hipMemsetAsync(volp, 0, (size_t)PVOX * 32 * sizeof(half_t), stream);

    // weight packs
    k_pack<<<216, 256, 0, stream>>>(w_c3a, wpA, 32, 27, 64);
    k_pack<<<432, 256, 0, stream>>>(w_c3b, wpB, 64, 27, 64);
    k_pack<<<288, 256, 0, stream>>>(w_r1, wpR1, 64, 9, 128);

    // VFE
    k_vfe_stats<<<512, 256, 0, stream>>>(voxels, w_lin, b_lin, S);
    k_bn_final<<<1, 64, 0, stream>>>(S + S_BN0S, S + S_BN0Q, g_bn0, be_bn0,
                                     S + C0A, S + C0B, 32, 1.f / 420000.f);
    k_vfe_max<<<1500, 256, 0, stream>>>(voxels, w_lin, b_lin, S + C0A, S + C0B, feats);
    k_scatter<<<1500, 256, 0, stream>>>(feats, coords, volp);

    // conv3a (IC=32) -> y1 f16 [p][64]
    k_conv_mfma<1, 27, 4, false, false><<<dim3(11, 50, 10), 64, 0, stream>>>(volp, wpA, b_c3a, Y);
    k_stats<<<256, 256, 0, stream>>>(Y, S + S_BN1S, S + S_BN1Q);
    k_bn_final<<<1, 64, 0, stream>>>(S + S_BN1S, S + S_BN1Q, g_bn1, be_bn1,
                                     S + C1A, S + C1B, 64, 1.f / 352000.f);
    k_activate<<<13484, 256, 0, stream>>>(Y, S + C1A, S + C1B, x1p);

    // conv3b (IC=64) -> y2 f16 [p][64] (overwrites y1)
    k_conv_mfma<2, 27, 4, false, false><<<dim3(11, 50, 10), 64, 0, stream>>>(x1p, wpB, b_c3b, Y);
    k_stats<<<256, 256, 0, stream>>>(Y, S + S_BN2S, S + S_BN2Q);
    k_bn_final<<<1, 64, 0, stream>>>(S + S_BN2S, S + S_BN2Q, g_bn2, be_bn2,
                                     S + C2A, S + C2B, 64, 1.f / 352000.f);

    // BN2+relu+depth-mean -> padded plane f16 [yp][xp][64]
    k_depthmean<<<8989, 256, 0, stream>>>(Y, S + C2A, S + C2B, plane);

    // RPN: r1 (2D conv, 128 oc via blockIdx.z halves) + relu -> [p][128] f16
    k_conv_mfma<2, 9, 8, true, true><<<dim3(11, 50, 2), 64, 0, stream>>>(plane, wpR1, b_r1, r1out);
    k_r2<<<138, 256, 0, stream>>>(r1out, w_r2, b_r2, outp);
}

// Round 3
// 540.876 us; speedup vs baseline: 12.4942x; 1.1570x over previous
//
#include <hip/hip_runtime.h>
#include <math.h>

// ---------------- problem constants ----------------
#define V_VOX 12000
#define T_PTS 35
#define DD 10
#define HH 200
#define WW 176
#define EPSV 1e-5f

#define DP 12
#define HP 202
#define WP 178
#define PPLN (HP * WP)          // 35956 padded plane pixels
#define PVOX (DP * PPLN)        // 431472 padded volume pixels
#define NPIX (DD * HH * WW)     // 352000
#define HWPIX (HH * WW)         // 35200

typedef _Float16 half_t;
typedef _Float16 f16x8 __attribute__((ext_vector_type(8)));
typedef float f32x4 __attribute__((ext_vector_type(4)));

// ---------------- workspace layout (BYTE offsets, all 256-aligned) ----------------
#define WPA_OFF 0           // 27*1*4*512 halves = 110592 B
#define WPB_OFF 110592      // 27*2*4*512 halves = 221184 B
#define WPR1_OFF 331776     // 9*2*8*512 halves = 147456 B
#define STATS_OFF 479232    // 1024 floats
#define FEATS_OFF 483328    // 12000*32 f32 = 1536000 B
#define VOLP_OFF 2019328    // PVOX*32 halves = 27614208 B
#define X1P_OFF 29633536    // PVOX*64 halves = 55228416 B
#define Y_OFF 84861952      // NPIX*64 halves = 45056000 B  (y1 then y2)
#define PLANE_OFF 129917952 // PPLN*64 halves = 4602368 B
#define R1OUT_OFF 134520320 // HWPIX*128 halves = 9011200 B

// stats float sub-offsets
#define S_BN0S 0
#define S_BN0Q 32
#define S_BN1S 64
#define S_BN1Q 128
#define S_BN2S 192
#define S_BN2Q 256
#define C0A 320
#define C0B 352
#define C1A 384
#define C1B 448
#define C2A 512
#define C2B 576

// ---------------- weight pack: w[oc][ic][tap] -> per-lane MFMA B fragments ----------------
// wp index = (((tap*KH + kh)*OCT + ot)*64 + lane)*8 + j
// oc = ot*16 + (lane&15); ic = kh*32 + (lane>>4)*8 + j
__global__ void k_pack(const float* __restrict__ w, half_t* __restrict__ wp,
                       int IC, int NT, int OC) {
    int id = blockIdx.x * 256 + threadIdx.x;
    int OCT = OC >> 4, KH = IC >> 5;
    int total = NT * KH * OCT * 512;
    if (id >= total) return;
    int j = id & 7;
    int lane = (id >> 3) & 63;
    int rest = id >> 9;
    int ot = rest % OCT; rest /= OCT;
    int kh = rest % KH;
    int tap = rest / KH;
    int oc = ot * 16 + (lane & 15);
    int ic = kh * 32 + (lane >> 4) * 8 + j;
    wp[id] = (half_t)w[(oc * IC + ic) * NT + tap];
}

// ---------------- VFE: BN0 batch stats ----------------
__global__ void k_vfe_stats(const float4* __restrict__ vox, const float* __restrict__ w_lin,
                            const float* __restrict__ b_lin, float* __restrict__ S) {
    int tid = blockIdx.x * 256 + threadIdx.x;
    int c = threadIdx.x & 31;
    float4 w = ((const float4*)w_lin)[c];
    float bl = b_lin[c];
    float s = 0.f, q = 0.f;
    const int np = V_VOX * T_PTS;
    int stride = gridDim.x * 8;
    for (int p = tid >> 5; p < np; p += stride) {
        float4 v = vox[p];
        float d = v.x * w.x + v.y * w.y + v.z * w.z + v.w * w.w + bl;
        s += d;
        q += d * d;
    }
    s += __shfl_xor(s, 32);
    q += __shfl_xor(q, 32);
    if ((threadIdx.x & 63) < 32) {
        atomicAdd(&S[S_BN0S + c], s);
        atomicAdd(&S[S_BN0Q + c], q);
    }
}

// ---------------- BN finalize ----------------
__global__ void k_bn_final(const float* __restrict__ ss, const float* __restrict__ sq,
                           const float* __restrict__ g, const float* __restrict__ be,
                           float* __restrict__ ca, float* __restrict__ cb, int C, float invN) {
    int c = threadIdx.x;
    if (c >= C) return;
    float m = ss[c] * invN;
    float v = sq[c] * invN - m * m;
    float a = g[c] * rsqrtf(v + EPSV);
    ca[c] = a;
    cb[c] = be[c] - m * a;
}

// ---------------- VFE: relu(bn(h)) max over T ----------------
__global__ void k_vfe_max(const float4* __restrict__ vox, const float* __restrict__ w_lin,
                          const float* __restrict__ b_lin, const float* __restrict__ ca,
                          const float* __restrict__ cb, float* __restrict__ feats) {
    int id = blockIdx.x * 256 + threadIdx.x;
    if (id >= V_VOX * 32) return;
    int c = id & 31;
    int v = id >> 5;
    float4 w = ((const float4*)w_lin)[c];
    float bl = b_lin[c], A = ca[c], B = cb[c];
    float m = 0.f;
    for (int t = 0; t < T_PTS; t++) {
        float4 p = vox[v * T_PTS + t];
        float d = p.x * w.x + p.y * w.y + p.z * w.z + p.w * w.w + bl;
        m = fmaxf(m, A * d + B);
    }
    feats[id] = m;
}

// ---------------- scatter feats into padded channel-last f16 volume ----------------
__global__ void k_scatter(const float* __restrict__ feats, const int* __restrict__ coords,
                          half_t* __restrict__ volp) {
    int id = blockIdx.x * 256 + threadIdx.x;
    if (id >= V_VOX * 32) return;
    int c = id & 31;
    int v = id >> 5;
    int z = coords[v * 3 + 0];
    int y = coords[v * 3 + 1];
    int x = coords[v * 3 + 2];
    volp[(((z + 1) * HP + (y + 1)) * WP + (x + 1)) * 32 + c] = (half_t)feats[id];
}

// ---------------- implicit-GEMM conv via MFMA f16, latency-optimized ----------------
// 4 waves/block, each wave: 16x * 4y pixels x 64 oc. Loop (dz,dx,kh): load 6 unique
// input rows + all 12 B fragments, then 48 MFMA (row-sharing across dy).
// Optionally fuses per-channel batch stats (sum/sumsq of y=conv+bias) via atomics.
template <int KH, int DZ, int OCTP, bool RELU, bool STATS>
__global__ __launch_bounds__(256, 3) void k_conv(const half_t* __restrict__ in,
                                                 const half_t* __restrict__ wp,
                                                 const float* __restrict__ bias,
                                                 half_t* __restrict__ out,
                                                 float* __restrict__ ssum,
                                                 float* __restrict__ ssq) {
    constexpr int CIN = KH * 32;
    constexpr int OC = OCTP * 16;
    const int lane = threadIdx.x & 63;
    const int wv = threadIdx.x >> 6;
    const int x0 = blockIdx.x * 16;
    const int y0 = (blockIdx.y * 4 + wv) * 4;
    const int z0 = (DZ == 3) ? blockIdx.z : 0;
    const int ocb = (DZ == 3) ? 0 : blockIdx.z * 4;
    if (y0 >= HH) return;

    const int colc = lane & 15, grp = lane >> 4;
    const size_t rstride = (size_t)WP * CIN;

    f32x4 acc[4][4];
#pragma unroll
    for (int m = 0; m < 4; m++)
#pragma unroll
        for (int n = 0; n < 4; n++) acc[m][n] = (f32x4)(0.f);

#pragma unroll 1
    for (int dz = 0; dz < DZ; ++dz) {
#pragma unroll 1
        for (int dx = 0; dx < 3; ++dx) {
#pragma unroll
            for (int kh = 0; kh < KH; ++kh) {
                const half_t* ib = in + (((size_t)(z0 + dz) * HP + y0) * WP + (x0 + dx)) * CIN
                                   + colc * CIN + kh * 32 + grp * 8;
                f16x8 Af[6];
#pragma unroll
                for (int r = 0; r < 6; ++r) Af[r] = *(const f16x8*)(ib + r * rstride);
                f16x8 Bf[3][4];
#pragma unroll
                for (int dy = 0; dy < 3; ++dy) {
                    const half_t* wb = wp + ((size_t)((dz * 9 + dy * 3 + dx) * KH + kh) * OCTP + ocb) * 512
                                       + lane * 8;
#pragma unroll
                    for (int n = 0; n < 4; ++n) Bf[dy][n] = *(const f16x8*)(wb + n * 512);
                }
#pragma unroll
                for (int dy = 0; dy < 3; ++dy)
#pragma unroll
                    for (int m = 0; m < 4; ++m)
#pragma unroll
                        for (int n = 0; n < 4; ++n)
                            acc[m][n] = __builtin_amdgcn_mfma_f32_16x16x32_f16(
                                Af[dy + m], Bf[dy][n], acc[m][n], 0, 0, 0);
            }
        }
    }

    // epilogue: C/D layout col=lane&15 (oc), row=(lane>>4)*4+i (x)
#pragma unroll
    for (int n = 0; n < 4; ++n) {
        int oc = (ocb + n) * 16 + colc;
        float bv = bias[oc];
        float s = 0.f, q = 0.f;
#pragma unroll
        for (int m = 0; m < 4; ++m) {
            int yy = y0 + m;
#pragma unroll
            for (int i = 0; i < 4; ++i) {
                int xx = x0 + grp * 4 + i;
                float v = acc[m][n][i] + bv;
                if (STATS) { s += v; q += v * v; }
                float w = RELU ? fmaxf(v, 0.f) : v;
                out[((size_t)(z0 * HH + yy) * WW + xx) * OC + oc] = (half_t)w;
            }
        }
        if (STATS) {
            s += __shfl_xor(s, 16); s += __shfl_xor(s, 32);
            q += __shfl_xor(q, 16); q += __shfl_xor(q, 32);
            if (lane < 16) {
                atomicAdd(&ssum[oc], s);
                atomicAdd(&ssq[oc], q);
            }
        }
    }
}

// ---------------- activate: x1p = relu(a*y1+b) into padded channel-last f16 (halo 0) ----------------
__global__ void k_activate(const half_t* __restrict__ y1, const float* __restrict__ ca,
                           const float* __restrict__ cb, half_t* __restrict__ xp) {
    int id = blockIdx.x * 256 + threadIdx.x;
    if (id >= PVOX * 8) return;
    int c0 = (id & 7) * 8;
    int pix = id >> 3;
    int zp = pix / PPLN;
    int rem = pix - zp * PPLN;
    int yp = rem / WP;
    int xq = rem - yp * WP;
    f16x8 o;
    if (zp >= 1 && zp <= DD && yp >= 1 && yp <= HH && xq >= 1 && xq <= WW) {
        size_t p = ((size_t)((zp - 1) * HH + (yp - 1)) * WW + (xq - 1));
        f16x8 v = *(const f16x8*)(y1 + p * 64 + c0);
#pragma unroll
        for (int j = 0; j < 8; j++)
            o[j] = (half_t)fmaxf(ca[c0 + j] * (float)v[j] + cb[c0 + j], 0.f);
    } else {
#pragma unroll
        for (int j = 0; j < 8; j++) o[j] = (half_t)0.f;
    }
    *(f16x8*)(xp + (size_t)pix * 64 + c0) = o;
}

// ---------------- BN2 + relu + depth mean -> padded channel-last plane f16 ----------------
__global__ void k_depthmean(const half_t* __restrict__ y2, const float* __restrict__ ca,
                            const float* __restrict__ cb, half_t* __restrict__ plane) {
    int id = blockIdx.x * 256 + threadIdx.x;  // PPLN*64 = 2301184, divisible by 256
    int c = id & 63;
    int pix = id >> 6;
    int yp = pix / WP;
    int xq = pix - yp * WP;
    float val = 0.f;
    if (yp >= 1 && yp <= HH && xq >= 1 && xq <= WW) {
        float A = ca[c], B = cb[c], s = 0.f;
        const half_t* base = y2 + ((size_t)(yp - 1) * WW + (xq - 1)) * 64 + c;
#pragma unroll
        for (int z = 0; z < DD; z++)
            s += fmaxf(A * (float)base[(size_t)z * HWPIX * 64] + B, 0.f);
        val = s * 0.1f;
    }
    plane[(size_t)pix * 64 + c] = (half_t)val;
}

// ---------------- 1x1 conv 128->8 + box transforms ----------------
__global__ void k_r2(const half_t* __restrict__ r1o, const float* __restrict__ w,
                     const float* __restrict__ bias, float* __restrict__ outp) {
    __shared__ float wsm[1024];
    for (int i = threadIdx.x; i < 1024; i += 256) wsm[i] = w[i];
    __syncthreads();
    int p = blockIdx.x * 256 + threadIdx.x;
    if (p >= HWPIX) return;
    float acc[8];
#pragma unroll
    for (int o = 0; o < 8; o++) acc[o] = bias[o];
    const half_t* rb = r1o + (size_t)p * 128;
#pragma unroll 4
    for (int icb = 0; icb < 128; icb += 8) {
        f16x8 v = *(const f16x8*)(rb + icb);
#pragma unroll
        for (int j = 0; j < 8; j++) {
            float vv = (float)v[j];
#pragma unroll
            for (int o = 0; o < 8; o++) acc[o] += vv * wsm[o * 128 + icb + j];
        }
    }
    outp[0 * HWPIX + p] = acc[0];
    outp[1 * HWPIX + p] = acc[1];
    outp[2 * HWPIX + p] = acc[2];
    outp[3 * HWPIX + p] = expf(acc[3]);
    outp[4 * HWPIX + p] = expf(acc[4]);
    outp[5 * HWPIX + p] = expf(acc[5]);
    outp[6 * HWPIX + p] = tanhf(acc[6]);
    outp[7 * HWPIX + p] = 1.f / (1.f + expf(-acc[7]));
}

// ---------------- host launch ----------------
extern "C" void kernel_launch(void* const* d_in, const int* in_sizes, int n_in,
                              void* d_out, int out_size, void* d_ws, size_t ws_size,
                              hipStream_t stream) {
    const float4* voxels = (const float4*)d_in[0];
    const int* coords = (const int*)d_in[1];
    const float* w_lin = (const float*)d_in[2];
    const float* b_lin = (const float*)d_in[3];
    const float* g_bn0 = (const float*)d_in[4];
    const float* be_bn0 = (const float*)d_in[5];
    const float* w_c3a = (const float*)d_in[6];
    const float* b_c3a = (const float*)d_in[7];
    const float* g_bn1 = (const float*)d_in[8];
    const float* be_bn1 = (const float*)d_in[9];
    const float* w_c3b = (const float*)d_in[10];
    const float* b_c3b = (const float*)d_in[11];
    const float* g_bn2 = (const float*)d_in[12];
    const float* be_bn2 = (const float*)d_in[13];
    const float* w_r1 = (const float*)d_in[14];
    const float* b_r1 = (const float*)d_in[15];
    const float* w_r2 = (const float*)d_in[16];
    const float* b_r2 = (const float*)d_in[17];

    char* ws = (char*)d_ws;
    half_t* wpA = (half_t*)(ws + WPA_OFF);
    half_t* wpB = (half_t*)(ws + WPB_OFF);
    half_t* wpR1 = (half_t*)(ws + WPR1_OFF);
    float* S = (float*)(ws + STATS_OFF);
    float* feats = (float*)(ws + FEATS_OFF);
    half_t* volp = (half_t*)(ws + VOLP_OFF);
    half_t* x1p = (half_t*)(ws + X1P_OFF);
    half_t* Y = (half_t*)(ws + Y_OFF);
    half_t* plane = (half_t*)(ws + PLANE_OFF);
    half_t* r1out = (half_t*)(ws + R1OUT_OFF);
    float* outp = (float*)d_out;

    hipMemsetAsync(S, 0, 320 * sizeof(float), stream);
    hipMemsetAsync(volp, 0, (size_t)PVOX * 32 * sizeof(half_t), stream);

    // weight packs
    k_pack<<<216, 256, 0, stream>>>(w_c3a, wpA, 32, 27, 64);
    k_pack<<<432, 256, 0, stream>>>(w_c3b, wpB, 64, 27, 64);
    k_pack<<<288, 256, 0, stream>>>(w_r1, wpR1, 64, 9, 128);

    // VFE
    k_vfe_stats<<<512, 256, 0, stream>>>(voxels, w_lin, b_lin, S);
    k_bn_final<<<1, 64, 0, stream>>>(S + S_BN0S, S + S_BN0Q, g_bn0, be_bn0,
                                     S + C0A, S + C0B, 32, 1.f / 420000.f);
    k_vfe_max<<<1500, 256, 0, stream>>>(voxels, w_lin, b_lin, S + C0A, S + C0B, feats);
    k_scatter<<<1500, 256, 0, stream>>>(feats, coords, volp);

    // conv3a (IC=32) -> y1 f16 [p][64], fused BN1 stats
    k_conv<1, 3, 4, false, true><<<dim3(11, 13, 10), 256, 0, stream>>>(
        volp, wpA, b_c3a, Y, S + S_BN1S, S + S_BN1Q);
    k_bn_final<<<1, 64, 0, stream>>>(S + S_BN1S, S + S_BN1Q, g_bn1, be_bn1,
                                     S + C1A, S + C1B, 64, 1.f / 352000.f);
    k_activate<<<13484, 256, 0, stream>>>(Y, S + C1A, S + C1B, x1p);

    // conv3b (IC=64) -> y2 f16 [p][64] (overwrites y1), fused BN2 stats
    k_conv<2, 3, 4, false, true><<<dim3(11, 13, 10), 256, 0, stream>>>(
        x1p, wpB, b_c3b, Y, S + S_BN2S, S + S_BN2Q);
    k_bn_final<<<1, 64, 0, stream>>>(S + S_BN2S, S + S_BN2Q, g_bn2, be_bn2,
                                     S + C2A, S + C2B, 64, 1.f / 352000.f);

    // BN2+relu+depth-mean -> padded plane f16 [yp][xp][64]
    k_depthmean<<<8989, 256, 0, stream>>>(Y, S + C2A, S + C2B, plane);

    // RPN: r1 (2D conv, 128 oc via blockIdx.z halves) + relu -> [p][128] f16
    k_conv<2, 1, 8, true, false><<<dim3(11, 13, 2), 256, 0, stream>>>(
        plane, wpR1, b_r1, r1out, nullptr, nullptr);
    k_r2<<<138, 256, 0, stream>>>(r1out, w_r2, b_r2, outp);
}

// Round 4
// 512.394 us; speedup vs baseline: 13.1887x; 1.0556x over previous
//
#include <hip/hip_runtime.h>
#include <math.h>

// ---------------- problem constants ----------------
#define V_VOX 12000
#define T_PTS 35
#define DD 10
#define HH 200
#define WW 176
#define EPSV 1e-5f

#define DP 12
#define HP 202
#define WP 178
#define PPLN (HP * WP)          // 35956 padded plane pixels
#define PVOX (DP * PPLN)        // 431472 padded volume pixels
#define NPIX (DD * HH * WW)     // 352000
#define HWPIX (HH * WW)         // 35200

typedef _Float16 half_t;
typedef _Float16 f16x8 __attribute__((ext_vector_type(8)));
typedef float f32x4 __attribute__((ext_vector_type(4)));

// ---------------- workspace layout (BYTE offsets, all 256-aligned) ----------------
#define WPA_OFF 0           // 27*1*4*512 halves = 110592 B
#define WPB_OFF 110592      // 27*2*4*512 halves = 221184 B
#define WPR1_OFF 331776     // 9*2*8*512 halves = 147456 B
#define STATS_OFF 479232    // 1024 floats
#define FEATS_OFF 483328    // 12000*32 f32 = 1536000 B
#define VOLP_OFF 2019328    // PVOX*32 halves = 27614208 B
#define X1P_OFF 29633536    // PVOX*64 halves = 55228416 B
#define Y_OFF 84861952      // NPIX*64 halves = 45056000 B  (y1 then y2)
#define PLANE_OFF 129917952 // PPLN*64 halves = 4602368 B
#define R1OUT_OFF 134520320 // HWPIX*128 halves = 9011200 B

// stats float sub-offsets
#define S_BN0S 0
#define S_BN0Q 32
#define S_BN1S 64
#define S_BN1Q 128
#define S_BN2S 192
#define S_BN2Q 256
#define C0A 320
#define C0B 352
#define C1A 384
#define C1B 448
#define C2A 512
#define C2B 576

// ---------------- weight pack: w[oc][ic][tap] -> per-lane MFMA B fragments ----------------
// wp index = (((tap*KH + kh)*OCT + ot)*64 + lane)*8 + j
// oc = ot*16 + (lane&15); ic = kh*32 + (lane>>4)*8 + j
__global__ void k_pack(const float* __restrict__ w, half_t* __restrict__ wp,
                       int IC, int NT, int OC) {
    int id = blockIdx.x * 256 + threadIdx.x;
    int OCT = OC >> 4, KH = IC >> 5;
    int total = NT * KH * OCT * 512;
    if (id >= total) return;
    int j = id & 7;
    int lane = (id >> 3) & 63;
    int rest = id >> 9;
    int ot = rest % OCT; rest /= OCT;
    int kh = rest % KH;
    int tap = rest / KH;
    int oc = ot * 16 + (lane & 15);
    int ic = kh * 32 + (lane >> 4) * 8 + j;
    wp[id] = (half_t)w[(oc * IC + ic) * NT + tap];
}

// ---------------- VFE: BN0 batch stats ----------------
__global__ void k_vfe_stats(const float4* __restrict__ vox, const float* __restrict__ w_lin,
                            const float* __restrict__ b_lin, float* __restrict__ S) {
    int tid = blockIdx.x * 256 + threadIdx.x;
    int c = threadIdx.x & 31;
    float4 w = ((const float4*)w_lin)[c];
    float bl = b_lin[c];
    float s = 0.f, q = 0.f;
    const int np = V_VOX * T_PTS;
    int stride = gridDim.x * 8;
    for (int p = tid >> 5; p < np; p += stride) {
        float4 v = vox[p];
        float d = v.x * w.x + v.y * w.y + v.z * w.z + v.w * w.w + bl;
        s += d;
        q += d * d;
    }
    s += __shfl_xor(s, 32);
    q += __shfl_xor(q, 32);
    if ((threadIdx.x & 63) < 32) {
        atomicAdd(&S[S_BN0S + c], s);
        atomicAdd(&S[S_BN0Q + c], q);
    }
}

// ---------------- BN finalize ----------------
__global__ void k_bn_final(const float* __restrict__ ss, const float* __restrict__ sq,
                           const float* __restrict__ g, const float* __restrict__ be,
                           float* __restrict__ ca, float* __restrict__ cb, int C, float invN) {
    int c = threadIdx.x;
    if (c >= C) return;
    float m = ss[c] * invN;
    float v = sq[c] * invN - m * m;
    float a = g[c] * rsqrtf(v + EPSV);
    ca[c] = a;
    cb[c] = be[c] - m * a;
}

// ---------------- VFE: relu(bn(h)) max over T ----------------
__global__ void k_vfe_max(const float4* __restrict__ vox, const float* __restrict__ w_lin,
                          const float* __restrict__ b_lin, const float* __restrict__ ca,
                          const float* __restrict__ cb, float* __restrict__ feats) {
    int id = blockIdx.x * 256 + threadIdx.x;
    if (id >= V_VOX * 32) return;
    int c = id & 31;
    int v = id >> 5;
    float4 w = ((const float4*)w_lin)[c];
    float bl = b_lin[c], A = ca[c], B = cb[c];
    float m = 0.f;
    for (int t = 0; t < T_PTS; t++) {
        float4 p = vox[v * T_PTS + t];
        float d = p.x * w.x + p.y * w.y + p.z * w.z + p.w * w.w + bl;
        m = fmaxf(m, A * d + B);
    }
    feats[id] = m;
}

// ---------------- scatter feats into padded channel-last f16 volume ----------------
__global__ void k_scatter(const float* __restrict__ feats, const int* __restrict__ coords,
                          half_t* __restrict__ volp) {
    int id = blockIdx.x * 256 + threadIdx.x;
    if (id >= V_VOX * 32) return;
    int c = id & 31;
    int v = id >> 5;
    int z = coords[v * 3 + 0];
    int y = coords[v * 3 + 1];
    int x = coords[v * 3 + 2];
    volp[(((z + 1) * HP + (y + 1)) * WP + (x + 1)) * 32 + c] = (half_t)feats[id];
}

// ---------------- LDS-staged implicit-GEMM conv via MFMA f16 ----------------
// Block: 256 thr / 4 waves; output tile 16x * 16y * 64oc (wave = 16x*4y).
// Per dz: stage 18x18xCIN slab coalesced into LDS (pixel stride padded to CLDS
// channels so ds_read_b128 A-fragments are bank-conflict-free), sync, compute.
// B-fragments stream from global (coalesced 1KB/load, L2-hot).
template <int KH, int CLDS, int DZ, int OCTP, bool RELU, bool STATS>
__global__ __launch_bounds__(256, 4) void k_conv(const half_t* __restrict__ in,
                                                 const half_t* __restrict__ wp,
                                                 const float* __restrict__ bias,
                                                 half_t* __restrict__ out,
                                                 float* __restrict__ ssum,
                                                 float* __restrict__ ssq) {
    constexpr int CIN = KH * 32;
    constexpr int C8 = KH * 4;          // f16x8 chunks per pixel
    constexpr int TOT8 = 18 * 18 * C8;  // staged vec8 elements per slab
    constexpr int OC = OCTP * 16;
    __shared__ half_t tile[18 * 18 * CLDS];

    const int tid = threadIdx.x;
    const int lane = tid & 63;
    const int wv = tid >> 6;
    const int x0 = blockIdx.x * 16;
    const int y0b = blockIdx.y * 16;
    const int z0 = (DZ == 3) ? blockIdx.z : 0;
    const int ocb = (DZ == 3) ? 0 : blockIdx.z * 4;
    const int y0w = y0b + wv * 4;
    const bool valid = (y0w < HH);
    const int colc = lane & 15, grp = lane >> 4;

    f32x4 acc[4][4];
#pragma unroll
    for (int m = 0; m < 4; m++)
#pragma unroll
        for (int n = 0; n < 4; n++) acc[m][n] = (f32x4)(0.f);

#pragma unroll 1
    for (int dz = 0; dz < DZ; ++dz) {
        // ---- stage slab (z0+dz): rows y0b..y0b+17 (clamped), px x0..x0+17, all CIN ch ----
        const half_t* sl = in + (size_t)(z0 + dz) * (DZ == 3 ? (size_t)HP * WP * CIN : 0);
#pragma unroll
        for (int it = 0; it < (TOT8 + 255) / 256; ++it) {
            int e = it * 256 + tid;
            if (e < TOT8) {
                int ch8 = e % C8;
                int pxr = e / C8;           // row*18 + px
                int px = pxr % 18;
                int row = pxr / 18;
                int srow = y0b + row;
                if (srow > HP - 1) srow = HP - 1;  // clamp (only by==12); pad rows are zero
                const half_t* s = sl + ((size_t)srow * WP + x0 + px) * CIN + ch8 * 8;
                *(f16x8*)&tile[pxr * CLDS + ch8 * 8] = *(const f16x8*)s;
            }
        }
        __syncthreads();

        if (valid) {
#pragma unroll 1
            for (int dx = 0; dx < 3; ++dx) {
#pragma unroll
                for (int kh = 0; kh < KH; ++kh) {
                    f16x8 Af[6];
#pragma unroll
                    for (int r = 0; r < 6; ++r)
                        Af[r] = *(const f16x8*)&tile[((wv * 4 + r) * 18 + colc + dx) * CLDS
                                                     + kh * 32 + grp * 8];
                    f16x8 Bf[3][4];
#pragma unroll
                    for (int dy = 0; dy < 3; ++dy) {
                        const half_t* wb = wp + ((size_t)((dz * 9 + dy * 3 + dx) * KH + kh) * OCTP
                                                 + ocb) * 512 + lane * 8;
#pragma unroll
                        for (int n = 0; n < 4; ++n) Bf[dy][n] = *(const f16x8*)(wb + n * 512);
                    }
#pragma unroll
                    for (int dy = 0; dy < 3; ++dy)
#pragma unroll
                        for (int m = 0; m < 4; ++m)
#pragma unroll
                            for (int n = 0; n < 4; ++n)
                                acc[m][n] = __builtin_amdgcn_mfma_f32_16x16x32_f16(
                                    Af[dy + m], Bf[dy][n], acc[m][n], 0, 0, 0);
                }
            }
        }
        __syncthreads();
    }

    if (!valid) return;
    // epilogue: C/D layout col=lane&15 (oc), row=(lane>>4)*4+i (x)
#pragma unroll
    for (int n = 0; n < 4; ++n) {
        int oc = (ocb + n) * 16 + colc;
        float bv = bias[oc];
        float s = 0.f, q = 0.f;
#pragma unroll
        for (int m = 0; m < 4; ++m) {
            int yy = y0w + m;
#pragma unroll
            for (int i = 0; i < 4; ++i) {
                int xx = x0 + grp * 4 + i;
                float v = acc[m][n][i] + bv;
                if (STATS) { s += v; q += v * v; }
                float w = RELU ? fmaxf(v, 0.f) : v;
                out[((size_t)(z0 * HH + yy) * WW + xx) * OC + oc] = (half_t)w;
            }
        }
        if (STATS) {
            s += __shfl_xor(s, 16); s += __shfl_xor(s, 32);
            q += __shfl_xor(q, 16); q += __shfl_xor(q, 32);
            if (lane < 16) {
                atomicAdd(&ssum[oc], s);
                atomicAdd(&ssq[oc], q);
            }
        }
    }
}

// ---------------- activate: x1p = relu(a*y1+b) into padded channel-last f16 (halo 0) ----------------
__global__ void k_activate(const half_t* __restrict__ y1, const float* __restrict__ ca,
                           const float* __restrict__ cb, half_t* __restrict__ xp) {
    int id = blockIdx.x * 256 + threadIdx.x;
    if (id >= PVOX * 8) return;
    int c0 = (id & 7) * 8;
    int pix = id >> 3;
    int zp = pix / PPLN;
    int rem = pix - zp * PPLN;
    int yp = rem / WP;
    int xq = rem - yp * WP;
    f16x8 o;
    if (zp >= 1 && zp <= DD && yp >= 1 && yp <= HH && xq >= 1 && xq <= WW) {
        size_t p = ((size_t)((zp - 1) * HH + (yp - 1)) * WW + (xq - 1));
        f16x8 v = *(const f16x8*)(y1 + p * 64 + c0);
#pragma unroll
        for (int j = 0; j < 8; j++)
            o[j] = (half_t)fmaxf(ca[c0 + j] * (float)v[j] + cb[c0 + j], 0.f);
    } else {
#pragma unroll
        for (int j = 0; j < 8; j++) o[j] = (half_t)0.f;
    }
    *(f16x8*)(xp + (size_t)pix * 64 + c0) = o;
}

// ---------------- BN2 + relu + depth mean -> padded channel-last plane f16 ----------------
__global__ void k_depthmean(const half_t* __restrict__ y2, const float* __restrict__ ca,
                            const float* __restrict__ cb, half_t* __restrict__ plane) {
    int id = blockIdx.x * 256 + threadIdx.x;  // PPLN*64 = 2301184, divisible by 256
    int c = id & 63;
    int pix = id >> 6;
    int yp = pix / WP;
    int xq = pix - yp * WP;
    float val = 0.f;
    if (yp >= 1 && yp <= HH && xq >= 1 && xq <= WW) {
        float A = ca[c], B = cb[c], s = 0.f;
        const half_t* base = y2 + ((size_t)(yp - 1) * WW + (xq - 1)) * 64 + c;
#pragma unroll
        for (int z = 0; z < DD; z++)
            s += fmaxf(A * (float)base[(size_t)z * HWPIX * 64] + B, 0.f);
        val = s * 0.1f;
    }
    plane[(size_t)pix * 64 + c] = (half_t)val;
}

// ---------------- 1x1 conv 128->8 + box transforms ----------------
__global__ void k_r2(const half_t* __restrict__ r1o, const float* __restrict__ w,
                     const float* __restrict__ bias, float* __restrict__ outp) {
    __shared__ float wsm[1024];
    for (int i = threadIdx.x; i < 1024; i += 256) wsm[i] = w[i];
    __syncthreads();
    int p = blockIdx.x * 256 + threadIdx.x;
    if (p >= HWPIX) return;
    float acc[8];
#pragma unroll
    for (int o = 0; o < 8; o++) acc[o] = bias[o];
    const half_t* rb = r1o + (size_t)p * 128;
#pragma unroll 4
    for (int icb = 0; icb < 128; icb += 8) {
        f16x8 v = *(const f16x8*)(rb + icb);
#pragma unroll
        for (int j = 0; j < 8; j++) {
            float vv = (float)v[j];
#pragma unroll
            for (int o = 0; o < 8; o++) acc[o] += vv * wsm[o * 128 + icb + j];
        }
    }
    outp[0 * HWPIX + p] = acc[0];
    outp[1 * HWPIX + p] = acc[1];
    outp[2 * HWPIX + p] = acc[2];
    outp[3 * HWPIX + p] = expf(acc[3]);
    outp[4 * HWPIX + p] = expf(acc[4]);
    outp[5 * HWPIX + p] = expf(acc[5]);
    outp[6 * HWPIX + p] = tanhf(acc[6]);
    outp[7 * HWPIX + p] = 1.f / (1.f + expf(-acc[7]));
}

// ---------------- host launch ----------------
extern "C" void kernel_launch(void* const* d_in, const int* in_sizes, int n_in,
                              void* d_out, int out_size, void* d_ws, size_t ws_size,
                              hipStream_t stream) {
    const float4* voxels = (const float4*)d_in[0];
    const int* coords = (const int*)d_in[1];
    const float* w_lin = (const float*)d_in[2];
    const float* b_lin = (const float*)d_in[3];
    const float* g_bn0 = (const float*)d_in[4];
    const float* be_bn0 = (const float*)d_in[5];
    const float* w_c3a = (const float*)d_in[6];
    const float* b_c3a = (const float*)d_in[7];
    const float* g_bn1 = (const float*)d_in[8];
    const float* be_bn1 = (const float*)d_in[9];
    const float* w_c3b = (const float*)d_in[10];
    const float* b_c3b = (const float*)d_in[11];
    const float* g_bn2 = (const float*)d_in[12];
    const float* be_bn2 = (const float*)d_in[13];
    const float* w_r1 = (const float*)d_in[14];
    const float* b_r1 = (const float*)d_in[15];
    const float* w_r2 = (const float*)d_in[16];
    const float* b_r2 = (const float*)d_in[17];

    char* ws = (char*)d_ws;
    half_t* wpA = (half_t*)(ws + WPA_OFF);
    half_t* wpB = (half_t*)(ws + WPB_OFF);
    half_t* wpR1 = (half_t*)(ws + WPR1_OFF);
    float* S = (float*)(ws + STATS_OFF);
    float* feats = (float*)(ws + FEATS_OFF);
    half_t* volp = (half_t*)(ws + VOLP_OFF);
    half_t* x1p = (half_t*)(ws + X1P_OFF);
    half_t* Y = (half_t*)(ws + Y_OFF);
    half_t* plane = (half_t*)(ws + PLANE_OFF);
    half_t* r1out = (half_t*)(ws + R1OUT_OFF);
    float* outp = (float*)d_out;

    hipMemsetAsync(S, 0, 320 * sizeof(float), stream);
    hipMemsetAsync(volp, 0, (size_t)PVOX * 32 * sizeof(half_t), stream);

    // weight packs
    k_pack<<<216, 256, 0, stream>>>(w_c3a, wpA, 32, 27, 64);
    k_pack<<<432, 256, 0, stream>>>(w_c3b, wpB, 64, 27, 64);
    k_pack<<<288, 256, 0, stream>>>(w_r1, wpR1, 64, 9, 128);

    // VFE
    k_vfe_stats<<<512, 256, 0, stream>>>(voxels, w_lin, b_lin, S);
    k_bn_final<<<1, 64, 0, stream>>>(S + S_BN0S, S + S_BN0Q, g_bn0, be_bn0,
                                     S + C0A, S + C0B, 32, 1.f / 420000.f);
    k_vfe_max<<<1500, 256, 0, stream>>>(voxels, w_lin, b_lin, S + C0A, S + C0B, feats);
    k_scatter<<<1500, 256, 0, stream>>>(feats, coords, volp);

    // conv3a (IC=32, LDS pixel stride 40) -> y1 f16 [p][64], fused BN1 stats
    k_conv<1, 40, 3, 4, false, true><<<dim3(11, 13, 10), 256, 0, stream>>>(
        volp, wpA, b_c3a, Y, S + S_BN1S, S + S_BN1Q);
    k_bn_final<<<1, 64, 0, stream>>>(S + S_BN1S, S + S_BN1Q, g_bn1, be_bn1,
                                     S + C1A, S + C1B, 64, 1.f / 352000.f);
    k_activate<<<13484, 256, 0, stream>>>(Y, S + C1A, S + C1B, x1p);

    // conv3b (IC=64, LDS pixel stride 72) -> y2 f16 [p][64], fused BN2 stats
    k_conv<2, 72, 3, 4, false, true><<<dim3(11, 13, 10), 256, 0, stream>>>(
        x1p, wpB, b_c3b, Y, S + S_BN2S, S + S_BN2Q);
    k_bn_final<<<1, 64, 0, stream>>>(S + S_BN2S, S + S_BN2Q, g_bn2, be_bn2,
                                     S + C2A, S + C2B, 64, 1.f / 352000.f);

    // BN2+relu+depth-mean -> padded plane f16 [yp][xp][64]
    k_depthmean<<<8989, 256, 0, stream>>>(Y, S + C2A, S + C2B, plane);

    // RPN: r1 (2D conv, 128 oc via blockIdx.z) + relu -> [p][128] f16
    k_conv<2, 72, 1, 8, true, false><<<dim3(11, 13, 2), 256, 0, stream>>>(
        plane, wpR1, b_r1, r1out, nullptr, nullptr);
    k_r2<<<138, 256, 0, stream>>>(r1out, w_r2, b_r2, outp);
}

// Round 5
// 498.033 us; speedup vs baseline: 13.5690x; 1.0288x over previous
//
#include <hip/hip_runtime.h>
#include <math.h>

// ---------------- problem constants ----------------
#define V_VOX 12000
#define T_PTS 35
#define DD 10
#define HH 200
#define WW 176
#define EPSV 1e-5f

#define DP 12
#define HP 202
#define WP 178
#define PPLN (HP * WP)          // 35956 padded plane pixels
#define PVOX (DP * PPLN)        // 431472 padded volume pixels
#define NPIX (DD * HH * WW)     // 352000
#define HWPIX (HH * WW)         // 35200

typedef _Float16 half_t;
typedef _Float16 f16x8 __attribute__((ext_vector_type(8)));
typedef float f32x4 __attribute__((ext_vector_type(4)));

// ---------------- workspace layout (BYTE offsets, all 256-aligned) ----------------
#define WPA_OFF 0           // 27*1*4*512 halves = 110592 B
#define WPB_OFF 110592      // 27*2*4*512 halves = 221184 B
#define WPR1_OFF 331776     // 9*2*8*512 halves = 147456 B
#define STATS_OFF 479232    // 1024 floats
#define FEATS_OFF 483328    // 12000*32 f32 = 1536000 B
#define VOLP_OFF 2019328    // PVOX*32 halves = 27614208 B
#define X1P_OFF 29633536    // PVOX*64 halves = 55228416 B
#define Y_OFF 84861952      // NPIX*64 halves = 45056000 B  (y1 then y2)
#define PLANE_OFF 129917952 // PPLN*64 halves = 4602368 B
#define R1OUT_OFF 134520320 // HWPIX*128 halves = 9011200 B

// stats float sub-offsets
#define S_BN0S 0
#define S_BN0Q 32
#define S_BN1S 64
#define S_BN1Q 128
#define S_BN2S 192
#define S_BN2Q 256
#define C0A 320
#define C0B 352
#define C1A 384
#define C1B 448
#define C2A 512
#define C2B 576

// ---------------- weight pack: w[oc][ic][tap] -> per-lane MFMA B fragments ----------------
// wp index = (((tap*KH + kh)*OCT + ot)*64 + lane)*8 + j
// oc = ot*16 + (lane&15); ic = kh*32 + (lane>>4)*8 + j
__global__ void k_pack(const float* __restrict__ w, half_t* __restrict__ wp,
                       int IC, int NT, int OC) {
    int id = blockIdx.x * 256 + threadIdx.x;
    int OCT = OC >> 4, KH = IC >> 5;
    int total = NT * KH * OCT * 512;
    if (id >= total) return;
    int j = id & 7;
    int lane = (id >> 3) & 63;
    int rest = id >> 9;
    int ot = rest % OCT; rest /= OCT;
    int kh = rest % KH;
    int tap = rest / KH;
    int oc = ot * 16 + (lane & 15);
    int ic = kh * 32 + (lane >> 4) * 8 + j;
    wp[id] = (half_t)w[(oc * IC + ic) * NT + tap];
}

// ---------------- VFE: BN0 batch stats ----------------
__global__ void k_vfe_stats(const float4* __restrict__ vox, const float* __restrict__ w_lin,
                            const float* __restrict__ b_lin, float* __restrict__ S) {
    int tid = blockIdx.x * 256 + threadIdx.x;
    int c = threadIdx.x & 31;
    float4 w = ((const float4*)w_lin)[c];
    float bl = b_lin[c];
    float s = 0.f, q = 0.f;
    const int np = V_VOX * T_PTS;
    int stride = gridDim.x * 8;
    for (int p = tid >> 5; p < np; p += stride) {
        float4 v = vox[p];
        float d = v.x * w.x + v.y * w.y + v.z * w.z + v.w * w.w + bl;
        s += d;
        q += d * d;
    }
    s += __shfl_xor(s, 32);
    q += __shfl_xor(q, 32);
    if ((threadIdx.x & 63) < 32) {
        atomicAdd(&S[S_BN0S + c], s);
        atomicAdd(&S[S_BN0Q + c], q);
    }
}

// ---------------- BN finalize ----------------
__global__ void k_bn_final(const float* __restrict__ ss, const float* __restrict__ sq,
                           const float* __restrict__ g, const float* __restrict__ be,
                           float* __restrict__ ca, float* __restrict__ cb, int C, float invN) {
    int c = threadIdx.x;
    if (c >= C) return;
    float m = ss[c] * invN;
    float v = sq[c] * invN - m * m;
    float a = g[c] * rsqrtf(v + EPSV);
    ca[c] = a;
    cb[c] = be[c] - m * a;
}

// ---------------- VFE: relu(bn(h)) max over T ----------------
__global__ void k_vfe_max(const float4* __restrict__ vox, const float* __restrict__ w_lin,
                          const float* __restrict__ b_lin, const float* __restrict__ ca,
                          const float* __restrict__ cb, float* __restrict__ feats) {
    int id = blockIdx.x * 256 + threadIdx.x;
    if (id >= V_VOX * 32) return;
    int c = id & 31;
    int v = id >> 5;
    float4 w = ((const float4*)w_lin)[c];
    float bl = b_lin[c], A = ca[c], B = cb[c];
    float m = 0.f;
    for (int t = 0; t < T_PTS; t++) {
        float4 p = vox[v * T_PTS + t];
        float d = p.x * w.x + p.y * w.y + p.z * w.z + p.w * w.w + bl;
        m = fmaxf(m, A * d + B);
    }
    feats[id] = m;
}

// ---------------- scatter feats into padded channel-last f16 volume ----------------
__global__ void k_scatter(const float* __restrict__ feats, const int* __restrict__ coords,
                          half_t* __restrict__ volp) {
    int id = blockIdx.x * 256 + threadIdx.x;
    if (id >= V_VOX * 32) return;
    int c = id & 31;
    int v = id >> 5;
    int z = coords[v * 3 + 0];
    int y = coords[v * 3 + 1];
    int x = coords[v * 3 + 2];
    volp[(((z + 1) * HP + (y + 1)) * WP + (x + 1)) * 32 + c] = (half_t)feats[id];
}

// ---------------- LDS-staged implicit-GEMM conv, 2-deep register pipeline ----------------
// Block: 256 thr / 4 waves; output tile 16x * 16y * 64oc (wave = 16x*4y).
// Per dz: stage 18x18xCIN slab into LDS (pixel stride CLDS, conflict-free), sync.
// Compute: phases p=(dx,kh); fragment sets double-buffered so phase p+1's 18
// loads are in flight during phase p's 48-MFMA batch (counted waitcnts).
template <int KH, int CLDS, int DZ, int OCTP, bool RELU, bool STATS>
__global__ __launch_bounds__(256, 2) void k_conv(const half_t* __restrict__ in,
                                                 const half_t* __restrict__ wp,
                                                 const float* __restrict__ bias,
                                                 half_t* __restrict__ out,
                                                 float* __restrict__ ssum,
                                                 float* __restrict__ ssq) {
    constexpr int CIN = KH * 32;
    constexpr int C8 = KH * 4;          // f16x8 chunks per pixel
    constexpr int TOT8 = 18 * 18 * C8;  // staged vec8 elements per slab
    constexpr int OC = OCTP * 16;
    constexpr int NPH = 3 * KH;         // phases per dz: (dx,kh)
    __shared__ half_t tile[18 * 18 * CLDS];

    const int tid = threadIdx.x;
    const int lane = tid & 63;
    const int wv = tid >> 6;
    const int x0 = blockIdx.x * 16;
    const int y0b = blockIdx.y * 16;
    const int z0 = (DZ == 3) ? blockIdx.z : 0;
    const int ocb = (DZ == 3) ? 0 : blockIdx.z * 4;
    const int y0w = y0b + wv * 4;
    const bool valid = (y0w < HH);
    const int colc = lane & 15, grp = lane >> 4;

    f32x4 acc[4][4];
#pragma unroll
    for (int m = 0; m < 4; m++)
#pragma unroll
        for (int n = 0; n < 4; n++) acc[m][n] = (f32x4)(0.f);

    f16x8 Aa[2][6];
    f16x8 Bb[2][3][4];

    // A fragments for phase p from LDS (pixel=(wv*4+r)*18+colc+dx)
    auto LDA = [&](int buf, int p) {
        const int dx = p / KH, kh = p % KH;
        const half_t* base = &tile[(size_t)((wv * 4) * 18 + colc + dx) * CLDS + kh * 32 + grp * 8];
#pragma unroll
        for (int r = 0; r < 6; ++r)
            Aa[buf][r] = *(const f16x8*)(base + (size_t)r * 18 * CLDS);
    };
    // B fragments for phase p from global (L1/L2-hot packed weights)
    auto LDB = [&](int buf, int p, int dz) {
        const int dx = p / KH, kh = p % KH;
#pragma unroll
        for (int dy = 0; dy < 3; ++dy) {
            const half_t* wb = wp + ((size_t)((dz * 9 + dy * 3 + dx) * KH + kh) * OCTP + ocb) * 512
                               + lane * 8;
#pragma unroll
            for (int n = 0; n < 4; ++n) Bb[buf][dy][n] = *(const f16x8*)(wb + n * 512);
        }
    };
    auto FMA = [&](int buf) {
#pragma unroll
        for (int dy = 0; dy < 3; ++dy)
#pragma unroll
            for (int m = 0; m < 4; ++m)
#pragma unroll
                for (int n = 0; n < 4; ++n)
                    acc[m][n] = __builtin_amdgcn_mfma_f32_16x16x32_f16(
                        Aa[buf][dy + m], Bb[buf][dy][n], acc[m][n], 0, 0, 0);
    };

#pragma unroll 1
    for (int dz = 0; dz < DZ; ++dz) {
        // ---- stage slab (z0+dz): rows y0b..y0b+17 (clamped), px x0..x0+17, all CIN ch ----
        const half_t* sl = in + (size_t)(z0 + dz) * (DZ == 3 ? (size_t)HP * WP * CIN : 0);
#pragma unroll
        for (int it = 0; it < (TOT8 + 255) / 256; ++it) {
            int e = it * 256 + tid;
            if (e < TOT8) {
                int ch8 = e % C8;
                int pxr = e / C8;           // row*18 + px
                int px = pxr % 18;
                int row = pxr / 18;
                int srow = y0b + row;
                if (srow > HP - 1) srow = HP - 1;  // clamp (only by==12); pad rows are zero
                const half_t* s = sl + ((size_t)srow * WP + x0 + px) * CIN + ch8 * 8;
                *(f16x8*)&tile[pxr * CLDS + ch8 * 8] = *(const f16x8*)s;
            }
        }
        __syncthreads();

        if (valid) {
            LDA(0, 0);
            LDB(0, 0, dz);
#pragma unroll
            for (int p = 0; p < NPH; p += 2) {
                if (p + 1 < NPH) { LDA(1, p + 1); LDB(1, p + 1, dz); }
                FMA(0);
                if (p + 2 < NPH) { LDA(0, p + 2); LDB(0, p + 2, dz); }
                if (p + 1 < NPH) FMA(1);
            }
        }
        __syncthreads();
    }

    if (!valid) return;
    // epilogue: C/D layout col=lane&15 (oc), row=(lane>>4)*4+i (x)
#pragma unroll
    for (int n = 0; n < 4; ++n) {
        int oc = (ocb + n) * 16 + colc;
        float bv = bias[oc];
        float s = 0.f, q = 0.f;
#pragma unroll
        for (int m = 0; m < 4; ++m) {
            int yy = y0w + m;
#pragma unroll
            for (int i = 0; i < 4; ++i) {
                int xx = x0 + grp * 4 + i;
                float v = acc[m][n][i] + bv;
                if (STATS) { s += v; q += v * v; }
                float w = RELU ? fmaxf(v, 0.f) : v;
                out[((size_t)(z0 * HH + yy) * WW + xx) * OC + oc] = (half_t)w;
            }
        }
        if (STATS) {
            s += __shfl_xor(s, 16); s += __shfl_xor(s, 32);
            q += __shfl_xor(q, 16); q += __shfl_xor(q, 32);
            if (lane < 16) {
                atomicAdd(&ssum[oc], s);
                atomicAdd(&ssq[oc], q);
            }
        }
    }
}

// ---------------- activate: x1p = relu(a*y1+b) into padded channel-last f16 (halo 0) ----------------
__global__ void k_activate(const half_t* __restrict__ y1, const float* __restrict__ ca,
                           const float* __restrict__ cb, half_t* __restrict__ xp) {
    int id = blockIdx.x * 256 + threadIdx.x;
    if (id >= PVOX * 8) return;
    int c0 = (id & 7) * 8;
    int pix = id >> 3;
    int zp = pix / PPLN;
    int rem = pix - zp * PPLN;
    int yp = rem / WP;
    int xq = rem - yp * WP;
    f16x8 o;
    if (zp >= 1 && zp <= DD && yp >= 1 && yp <= HH && xq >= 1 && xq <= WW) {
        size_t p = ((size_t)((zp - 1) * HH + (yp - 1)) * WW + (xq - 1));
        f16x8 v = *(const f16x8*)(y1 + p * 64 + c0);
#pragma unroll
        for (int j = 0; j < 8; j++)
            o[j] = (half_t)fmaxf(ca[c0 + j] * (float)v[j] + cb[c0 + j], 0.f);
    } else {
#pragma unroll
        for (int j = 0; j < 8; j++) o[j] = (half_t)0.f;
    }
    *(f16x8*)(xp + (size_t)pix * 64 + c0) = o;
}

// ---------------- BN2 + relu + depth mean -> padded channel-last plane f16 ----------------
__global__ void k_depthmean(const half_t* __restrict__ y2, const float* __restrict__ ca,
                            const float* __restrict__ cb, half_t* __restrict__ plane) {
    int id = blockIdx.x * 256 + threadIdx.x;  // PPLN*64 = 2301184, divisible by 256
    int c = id & 63;
    int pix = id >> 6;
    int yp = pix / WP;
    int xq = pix - yp * WP;
    float val = 0.f;
    if (yp >= 1 && yp <= HH && xq >= 1 && xq <= WW) {
        float A = ca[c], B = cb[c], s = 0.f;
        const half_t* base = y2 + ((size_t)(yp - 1) * WW + (xq - 1)) * 64 + c;
#pragma unroll
        for (int z = 0; z < DD; z++)
            s += fmaxf(A * (float)base[(size_t)z * HWPIX * 64] + B, 0.f);
        val = s * 0.1f;
    }
    plane[(size_t)pix * 64 + c] = (half_t)val;
}

// ---------------- 1x1 conv 128->8 + box transforms ----------------
__global__ void k_r2(const half_t* __restrict__ r1o, const float* __restrict__ w,
                     const float* __restrict__ bias, float* __restrict__ outp) {
    __shared__ float wsm[1024];
    for (int i = threadIdx.x; i < 1024; i += 256) wsm[i] = w[i];
    __syncthreads();
    int p = blockIdx.x * 256 + threadIdx.x;
    if (p >= HWPIX) return;
    float acc[8];
#pragma unroll
    for (int o = 0; o < 8; o++) acc[o] = bias[o];
    const half_t* rb = r1o + (size_t)p * 128;
#pragma unroll 4
    for (int icb = 0; icb < 128; icb += 8) {
        f16x8 v = *(const f16x8*)(rb + icb);
#pragma unroll
        for (int j = 0; j < 8; j++) {
            float vv = (float)v[j];
#pragma unroll
            for (int o = 0; o < 8; o++) acc[o] += vv * wsm[o * 128 + icb + j];
        }
    }
    outp[0 * HWPIX + p] = acc[0];
    outp[1 * HWPIX + p] = acc[1];
    outp[2 * HWPIX + p] = acc[2];
    outp[3 * HWPIX + p] = expf(acc[3]);
    outp[4 * HWPIX + p] = expf(acc[4]);
    outp[5 * HWPIX + p] = expf(acc[5]);
    outp[6 * HWPIX + p] = tanhf(acc[6]);
    outp[7 * HWPIX + p] = 1.f / (1.f + expf(-acc[7]));
}

// ---------------- host launch ----------------
extern "C" void kernel_launch(void* const* d_in, const int* in_sizes, int n_in,
                              void* d_out, int out_size, void* d_ws, size_t ws_size,
                              hipStream_t stream) {
    const float4* voxels = (const float4*)d_in[0];
    const int* coords = (const int*)d_in[1];
    const float* w_lin = (const float*)d_in[2];
    const float* b_lin = (const float*)d_in[3];
    const float* g_bn0 = (const float*)d_in[4];
    const float* be_bn0 = (const float*)d_in[5];
    const float* w_c3a = (const float*)d_in[6];
    const float* b_c3a = (const float*)d_in[7];
    const float* g_bn1 = (const float*)d_in[8];
    const float* be_bn1 = (const float*)d_in[9];
    const float* w_c3b = (const float*)d_in[10];
    const float* b_c3b = (const float*)d_in[11];
    const float* g_bn2 = (const float*)d_in[12];
    const float* be_bn2 = (const float*)d_in[13];
    const float* w_r1 = (const float*)d_in[14];
    const float* b_r1 = (const float*)d_in[15];
    const float* w_r2 = (const float*)d_in[16];
    const float* b_r2 = (const float*)d_in[17];

    char* ws = (char*)d_ws;
    half_t* wpA = (half_t*)(ws + WPA_OFF);
    half_t* wpB = (half_t*)(ws + WPB_OFF);
    half_t* wpR1 = (half_t*)(ws + WPR1_OFF);
    float* S = (float*)(ws + STATS_OFF);
    float* feats = (float*)(ws + FEATS_OFF);
    half_t* volp = (half_t*)(ws + VOLP_OFF);
    half_t* x1p = (half_t*)(ws + X1P_OFF);
    half_t* Y = (half_t*)(ws + Y_OFF);
    half_t* plane = (half_t*)(ws + PLANE_OFF);
    half_t* r1out = (half_t*)(ws + R1OUT_OFF);
    float* outp = (float*)d_out;

    hipMemsetAsync(S, 0, 320 * sizeof(float), stream);
    hipMemsetAsync(volp, 0, (size_t)PVOX * 32 * sizeof(half_t), stream);

    // weight packs
    k_pack<<<216, 256, 0, stream>>>(w_c3a, wpA, 32, 27, 64);
    k_pack<<<432, 256, 0, stream>>>(w_c3b, wpB, 64, 27, 64);
    k_pack<<<288, 256, 0, stream>>>(w_r1, wpR1, 64, 9, 128);

    // VFE
    k_vfe_stats<<<512, 256, 0, stream>>>(voxels, w_lin, b_lin, S);
    k_bn_final<<<1, 64, 0, stream>>>(S + S_BN0S, S + S_BN0Q, g_bn0, be_bn0,
                                     S + C0A, S + C0B, 32, 1.f / 420000.f);
    k_vfe_max<<<1500, 256, 0, stream>>>(voxels, w_lin, b_lin, S + C0A, S + C0B, feats);
    k_scatter<<<1500, 256, 0, stream>>>(feats, coords, volp);

    // conv3a (IC=32, LDS pixel stride 40) -> y1 f16 [p][64], fused BN1 stats
    k_conv<1, 40, 3, 4, false, true><<<dim3(11, 13, 10), 256, 0, stream>>>(
        volp, wpA, b_c3a, Y, S + S_BN1S, S + S_BN1Q);
    k_bn_final<<<1, 64, 0, stream>>>(S + S_BN1S, S + S_BN1Q, g_bn1, be_bn1,
                                     C1A + S, S + C1B, 64, 1.f / 352000.f);
    k_activate<<<13484, 256, 0, stream>>>(Y, S + C1A, S + C1B, x1p);

    // conv3b (IC=64, LDS pixel stride 72) -> y2 f16 [p][64], fused BN2 stats
    k_conv<2, 72, 3, 4, false, true><<<dim3(11, 13, 10), 256, 0, stream>>>(
        x1p, wpB, b_c3b, Y, S + S_BN2S, S + S_BN2Q);
    k_bn_final<<<1, 64, 0, stream>>>(S + S_BN2S, S + S_BN2Q, g_bn2, be_bn2,
                                     S + C2A, S + C2B, 64, 1.f / 352000.f);

    // BN2+relu+depth-mean -> padded plane f16 [yp][xp][64]
    k_depthmean<<<8989, 256, 0, stream>>>(Y, S + C2A, S + C2B, plane);

    // RPN: r1 (2D conv, 128 oc via blockIdx.z) + relu -> [p][128] f16
    k_conv<2, 72, 1, 8, true, false><<<dim3(11, 13, 2), 256, 0, stream>>>(
        plane, wpR1, b_r1, r1out, nullptr, nullptr);
    k_r2<<<138, 256, 0, stream>>>(r1out, w_r2, b_r2, outp);
}